// Round 3
// baseline (523.558 us; speedup 1.0000x reference)
//
#include <hip/hip_runtime.h>
#include <math.h>

// Problem constants (folded from reference):
//   N=16, C=64, T=30, H=64, W=44, OUT_H=16, OUT_W=20
//   atten_in_t=12, atten_in_h=32, atten_in_w=40, aout_h=16 (== OUT_H -> no pad)
//   anchor_t=15, anchor_x=22, anchor_y=24
#define NN 16
#define CC 64
#define TT 30
#define HH 64
#define WW 44
#define OUTH 16
#define OUTW 20
#define HW 320   // OUTH*OUTW

// Workspace layout (floats)
#define FXT_OFF   0                       // [16][44][20] = 14080  (transposed Fx)
#define FY_OFF    14080                   // [16][16][64] = 16384
#define IDX0_OFF  30464                   // int[480]
#define IDX1_OFF  30944                   // int[480]
#define TW0_OFF   31424                   // float[480]
#define TW1_OFF   31904                   // float[480]
#define GAM_OFF   32384                   // float[16]
#define RNG_OFF   32400                   // int[16][4]: wlo4, whi4, hlo4, hhi4
#define G_OFF     32464                   // [16][64][30][320] = 9830400

// ---------------------------------------------------------------------------
// Kernel 1: per-n MLP -> attention params -> normalized FxT/Fy, time weights,
// plus Gaussian support ranges (exp cutoff e^-30 -> omitted normalized
// weight <= ~1e-12, far below tolerance; degenerates to full range if sigma
// is large, so always correct).
// ---------------------------------------------------------------------------
__global__ __launch_bounds__(64) void params_kernel(
    const float* __restrict__ param_x, const float* __restrict__ W1,
    const float* __restrict__ b1, const float* __restrict__ W2,
    const float* __restrict__ b2, float* __restrict__ ws,
    float* __restrict__ params_out) {
  int n = blockIdx.x;
  int tid = threadIdx.x;  // 64 threads
  __shared__ float px[64];
  __shared__ float hid[32];
  __shared__ float pv[7];

  px[tid] = param_x[n * 64 + tid];
  __syncthreads();
  if (tid < 32) {
    float s = b1[tid];
    #pragma unroll
    for (int k = 0; k < 64; ++k) s += px[k] * W1[k * 32 + tid];
    hid[tid] = tanhf(s);
  }
  __syncthreads();
  if (tid < 7) {
    float s = b2[tid];
    #pragma unroll
    for (int j = 0; j < 32; ++j) s += hid[j] * W2[j * 7 + tid];
    pv[tid] = s;
  }
  __syncthreads();

  float dt      = tanhf(pv[0]) * 6.0f  + 15.0f;
  float dx      = tanhf(pv[1]) * 20.0f + 22.0f;
  float dy      = tanhf(pv[2]) * 16.0f + 24.0f;
  float sigma2  = expf(pv[3]);
  float delta_t = expf(pv[4]) * 0.4f;
  float delta   = expf(pv[5]) * (10.0f / 11.0f);
  float gamma   = 1.0f / (1.0f + expf(-pv[6]));
  float inv2s2  = 1.0f / (2.0f * sigma2);

  if (tid < 20) {
    float mu = dx + ((float)tid - 10.0f) * delta;
    float vals[44];
    float s = 0.0f;
    #pragma unroll
    for (int w = 0; w < 44; ++w) {
      float d = (float)w - mu;
      float e = expf(-d * d * inv2s2);
      vals[w] = e; s += e;
    }
    float inv = 1.0f / fmaxf(s, 1e-8f);
    // transposed layout: fxT[n][w][q]
    float* FxT = ws + FXT_OFF + n * (44 * 20) + tid;
    #pragma unroll
    for (int w = 0; w < 44; ++w) FxT[w * 20] = vals[w] * inv;
  }
  if (tid < 16) {
    float mu = dy + ((float)tid - 8.0f) * delta;
    float vals[64];
    float s = 0.0f;
    #pragma unroll
    for (int h = 0; h < 64; ++h) {
      float d = (float)h - mu;
      float e = expf(-d * d * inv2s2);
      vals[h] = e; s += e;
    }
    float inv = 1.0f / fmaxf(s, 1e-8f);
    float* Fy = ws + FY_OFF + n * (16 * 64) + tid * 64;
    #pragma unroll
    for (int h = 0; h < 64; ++h) Fy[h] = vals[h] * inv;
  }
  if (tid < 30) {
    float mu = dt + ((float)tid - 15.0f) * delta_t;
    float i0f = floorf(mu);
    float frac = mu - i0f;
    int i0 = (int)i0f;
    int i1 = i0 + 1;
    float w0 = (i0 >= 0 && i0 < TT) ? (1.0f - frac) : 0.0f;
    float w1 = (i1 >= 0 && i1 < TT) ? frac : 0.0f;
    ((int*)(ws + IDX0_OFF))[n * TT + tid] = min(max(i0, 0), TT - 1);
    ((int*)(ws + IDX1_OFF))[n * TT + tid] = min(max(i1, 0), TT - 1);
    ws[TW0_OFF + n * TT + tid] = w0;
    ws[TW1_OFF + n * TT + tid] = w1;
  }
  if (tid == 0) {
    // Gaussian support (union over q / p), cutoff exponent 30 -> R = sqrt(60)*sigma
    float R = 7.7459667f * sqrtf(sigma2);
    int wlo = max(0,  (int)floorf(dx - 10.0f * delta - R));
    int whi = min(43, (int)ceilf (dx +  9.0f * delta + R));
    int hlo = max(0,  (int)floorf(dy -  8.0f * delta - R));
    int hhi = min(63, (int)ceilf (dy +  7.0f * delta + R));
    int* rng = (int*)(ws + RNG_OFF) + n * 4;
    rng[0] = wlo & ~3;   // float4-aligned expansion (safe direction)
    rng[1] = whi | 3;
    rng[2] = hlo & ~3;
    rng[3] = hhi | 3;

    ws[GAM_OFF + n] = gamma;
    params_out[0 * NN + n] = dt;
    params_out[1 * NN + n] = dx;
    params_out[2 * NN + n] = dy;
    params_out[3 * NN + n] = sigma2;
    params_out[4 * NN + n] = delta;
    params_out[5 * NN + n] = delta_t;
    params_out[6 * NN + n] = gamma;
  }
}

// ---------------------------------------------------------------------------
// Kernel 2 v4: block = (n, t, c-quad).
// Stage 1 (chunk-outer, scalar bounds): for each w-chunk in support,
//   load x float4 (h-masked), FMA into acc[20] with s_loaded fxT row.
//   Issues only ~(whi-wlo)/4 of 11 chunks' FMAs; no xrow[44] registers.
// Stage 2: g[p][q] = sum_h Fy[p][h]*t1[h][q], 2p x 5q register tile,
//   h-range restricted, half-wave h-split + shfl_xor(32) reduce.
// ---------------------------------------------------------------------------
__global__ __launch_bounds__(256) void spatial_kernel(
    const float* __restrict__ x, const float* __restrict__ ws,
    float* __restrict__ g) {
  int b = blockIdx.x;                 // 0 .. 16*30*16-1
  int n  = b / (TT * 16);
  int r  = b % (TT * 16);
  int t  = r / 16;
  int c0 = (r % 16) * 4;

  int tid  = threadIdx.x;
  int cl   = tid >> 6;        // 0..3
  int lane = tid & 63;

  __shared__ float st1[4 * 20 * 68];  // [cl][q][h], stride 68 (bank-spread)
  __shared__ float sFy[16 * 68];      // [p][h], stride 68

  const int* rng = (const int*)(ws + RNG_OFF) + n * 4;
  // scalarize bounds -> SGPR loop bounds, scalar branches, s_load fxT
  int wlo4 = __builtin_amdgcn_readfirstlane(rng[0]);
  int whi4 = __builtin_amdgcn_readfirstlane(rng[1]);
  int hlo4 = __builtin_amdgcn_readfirstlane(rng[2]);
  int hhi4 = __builtin_amdgcn_readfirstlane(rng[3]);

  // Load Fy into LDS: one float4 per thread (1024 floats)
  {
    const float4* Fy4 = (const float4*)(ws + FY_OFF + n * (16 * 64));
    float4 v = Fy4[tid];
    int p = tid >> 4, h4 = tid & 15;
    *(float4*)&sFy[p * 68 + h4 * 4] = v;
  }

  // ---- Stage 1: thread handles (c0+cl, h=lane) ----
  int c = c0 + cl;
  bool hact = (lane >= hlo4) && (lane <= hhi4);
  const float4* xp =
      (const float4*)(x + ((((size_t)n * CC + c) * TT + t) * HH + lane) * WW);
  const float* fxt = ws + FXT_OFF + n * (44 * 20);  // wave-uniform -> s_load

  float acc[20];
  #pragma unroll
  for (int q = 0; q < 20; ++q) acc[q] = 0.0f;

  int ilo = wlo4 >> 2, ihi = whi4 >> 2;   // SGPR
  for (int i = ilo; i <= ihi; ++i) {
    float4 v = make_float4(0.0f, 0.0f, 0.0f, 0.0f);
    if (hact) v = xp[i];
    float vx[4] = {v.x, v.y, v.z, v.w};
    const float* fr = fxt + i * 80;       // 80 contiguous weights, uniform addr
    #pragma unroll
    for (int k = 0; k < 4; ++k) {
      #pragma unroll
      for (int q = 0; q < 20; ++q)
        acc[q] = fmaf(vx[k], fr[k * 20 + q], acc[q]);
    }
  }
  if (hact) {
    #pragma unroll
    for (int q = 0; q < 20; ++q) st1[(cl * 20 + q) * 68 + lane] = acc[q];
  }
  __syncthreads();

  // ---- Stage 2: thread = (hh = lane>>5, pp = (lane>>2)&7, qg = lane&3)
  //      computes p in {pp, pp+8}, q in [qg*5, qg*5+5), partial over its
  //      h-half (interleaved hcc), then shfl_xor(32) combines halves.
  int hh = lane >> 5;
  int pp = (lane >> 2) & 7;
  int qg = lane & 3;
  int hc0 = hlo4 >> 2, hc1 = hhi4 >> 2;   // SGPR bounds

  float o[2][5];
  #pragma unroll
  for (int u = 0; u < 2; ++u)
    #pragma unroll
    for (int j = 0; j < 5; ++j) o[u][j] = 0.0f;

  for (int hcc = hc0 + hh; hcc <= hc1; hcc += 2) {
    float4 fy0 = *(const float4*)&sFy[pp * 68 + hcc * 4];
    float4 fy1 = *(const float4*)&sFy[(pp + 8) * 68 + hcc * 4];
    #pragma unroll
    for (int j = 0; j < 5; ++j) {
      int q = qg * 5 + j;
      float4 tv = *(const float4*)&st1[(cl * 20 + q) * 68 + hcc * 4];
      o[0][j] = fmaf(fy0.x, tv.x,
                fmaf(fy0.y, tv.y, fmaf(fy0.z, tv.z, fmaf(fy0.w, tv.w, o[0][j]))));
      o[1][j] = fmaf(fy1.x, tv.x,
                fmaf(fy1.y, tv.y, fmaf(fy1.z, tv.z, fmaf(fy1.w, tv.w, o[1][j]))));
    }
  }
  #pragma unroll
  for (int u = 0; u < 2; ++u)
    #pragma unroll
    for (int j = 0; j < 5; ++j)
      o[u][j] += __shfl_xor(o[u][j], 32);

  if (hh == 0) {
    float* gout = g + ((size_t)((n * CC + c) * TT + t)) * HW;
    #pragma unroll
    for (int u = 0; u < 2; ++u) {
      int p = pp + u * 8;
      #pragma unroll
      for (int j = 0; j < 5; ++j) gout[p * OUTW + qg * 5 + j] = o[u][j];
    }
  }
}

// ---------------------------------------------------------------------------
// Kernel 3 v3: block = (n, t', hw-half). float4 mix-fill; register-tiled
// 8oc x 5hw micro-GEMM.
// ---------------------------------------------------------------------------
__global__ __launch_bounds__(256) void output_kernel(
    const float* __restrict__ g, const float* __restrict__ ws,
    const float* __restrict__ Wf, const float* __restrict__ bf,
    float* __restrict__ out) {
  int b = blockIdx.x;             // 0 .. 16*30*2-1
  int n    = b / (TT * 2);
  int r    = b % (TT * 2);
  int tp   = r >> 1;
  int hw0  = (r & 1) * 160;
  int tid  = threadIdx.x;

  __shared__ float sWfT[64 * 65];   // [c][oc], pad 65 (16.6 KB)
  __shared__ float smix[64 * 160];  // [c][hw-half]   (40.96 KB)

  // Wf transposed into LDS
  #pragma unroll
  for (int i = tid; i < 64 * 64; i += 256) {
    int oc = i >> 6, c = i & 63;
    sWfT[c * 65 + oc] = Wf[i];
  }

  int i0 = ((const int*)(ws + IDX0_OFF))[n * TT + tp];
  int i1 = ((const int*)(ws + IDX1_OFF))[n * TT + tp];
  float w0 = ws[TW0_OFF + n * TT + tp];
  float w1 = ws[TW1_OFF + n * TT + tp];
  float gamma = ws[GAM_OFF + n];

  // time-resample + gamma into LDS, float4-vectorized (10 iters/thread)
  #pragma unroll
  for (int i4 = tid; i4 < 64 * 40; i4 += 256) {
    int c  = i4 / 40;
    int r4 = i4 - c * 40;
    size_t base = (size_t)(n * CC + c) * TT;
    float4 a  = *(const float4*)(g + (base + i0) * HW + hw0 + r4 * 4);
    float4 bb = *(const float4*)(g + (base + i1) * HW + hw0 + r4 * 4);
    float4 m;
    m.x = gamma * fmaf(w0, a.x, w1 * bb.x);
    m.y = gamma * fmaf(w0, a.y, w1 * bb.y);
    m.z = gamma * fmaf(w0, a.z, w1 * bb.z);
    m.w = gamma * fmaf(w0, a.w, w1 * bb.w);
    *(float4*)&smix[c * 160 + r4 * 4] = m;
  }
  __syncthreads();

  // micro-GEMM: thread tile 8 oc x 5 hw
  int ocg = tid >> 5;           // 0..7  -> oc0 = ocg*8
  int hwg = tid & 31;           // 0..31 -> hwl0 = hwg*5
  int oc0 = ocg * 8;
  int hwl0 = hwg * 5;
  float acc[8][5];
  #pragma unroll
  for (int u = 0; u < 8; ++u)
    #pragma unroll
    for (int j = 0; j < 5; ++j) acc[u][j] = 0.0f;

  #pragma unroll 4
  for (int c = 0; c < 64; ++c) {
    float4 wv0 = *(const float4*)&sWfT[c * 65 + oc0];
    float4 wv1 = *(const float4*)&sWfT[c * 65 + oc0 + 4];
    float m[5];
    #pragma unroll
    for (int j = 0; j < 5; ++j) m[j] = smix[c * 160 + hwl0 + j];
    float wv[8] = {wv0.x, wv0.y, wv0.z, wv0.w, wv1.x, wv1.y, wv1.z, wv1.w};
    #pragma unroll
    for (int u = 0; u < 8; ++u)
      #pragma unroll
      for (int j = 0; j < 5; ++j) acc[u][j] = fmaf(wv[u], m[j], acc[u][j]);
  }

  #pragma unroll
  for (int u = 0; u < 8; ++u) {
    int oc = oc0 + u;
    float bias = bf[oc];
    float* op = out + (((size_t)n * CC + oc) * TT + tp) * HW + hw0 + hwl0;
    #pragma unroll
    for (int j = 0; j < 5; ++j) op[j] = acc[u][j] + bias;
  }
}

// ---------------------------------------------------------------------------
extern "C" void kernel_launch(void* const* d_in, const int* in_sizes, int n_in,
                              void* d_out, int out_size, void* d_ws,
                              size_t ws_size, hipStream_t stream) {
  const float* x       = (const float*)d_in[0];
  const float* param_x = (const float*)d_in[1];
  const float* W1      = (const float*)d_in[2];
  const float* b1      = (const float*)d_in[3];
  const float* W2      = (const float*)d_in[4];
  const float* b2      = (const float*)d_in[5];
  const float* Wf      = (const float*)d_in[6];
  const float* bf      = (const float*)d_in[7];
  float* out = (float*)d_out;
  float* ws  = (float*)d_ws;
  float* params_out = out + (size_t)NN * CC * TT * HW;  // 9830400

  params_kernel<<<NN, 64, 0, stream>>>(param_x, W1, b1, W2, b2, ws, params_out);
  spatial_kernel<<<NN * TT * 16, 256, 0, stream>>>(x, ws, ws + G_OFF);
  output_kernel<<<NN * TT * 2, 256, 0, stream>>>(ws + G_OFF, ws, Wf, bf, out);
}

// Round 5
// 476.501 us; speedup vs baseline: 1.0988x; 1.0988x over previous
//
#include <hip/hip_runtime.h>
#include <math.h>

// Problem constants (folded from reference):
//   N=16, C=64, T=30, H=64, W=44, OUT_H=16, OUT_W=20
//   atten_in_t=12, atten_in_h=32, atten_in_w=40, aout_h=16 (== OUT_H -> no pad)
//   anchor_t=15, anchor_x=22, anchor_y=24
#define NN 16
#define CC 64
#define TT 30
#define HH 64
#define WW 44
#define OUTH 16
#define OUTW 20
#define HW 320   // OUTH*OUTW

// Workspace layout (floats)
#define FXT_OFF   0                       // [16][44][20] = 14080  (transposed Fx)
#define FY_OFF    14080                   // [16][16][64] = 16384
#define IDX0_OFF  30464                   // int[480]
#define IDX1_OFF  30944                   // int[480]
#define TW0_OFF   31424                   // float[480]
#define TW1_OFF   31904                   // float[480]
#define GAM_OFF   32384                   // float[16]
#define RNG_OFF   32400                   // int[16][6]: wlo4,whi4,hlo4,hhi4,tlo,thi
#define G_OFF     32512                   // [16][64][30][320] = 9830400

// ---------------------------------------------------------------------------
// Kernel 1: per-n MLP -> attention params -> normalized FxT/Fy, time weights,
// Gaussian support ranges (exp cutoff e^-30: omitted normalized weight
// <= ~1e-12, far below tolerance; degenerates to full range for large sigma),
// and the needed-t range [tlo,thi] = union of clipped gather indices.
// ---------------------------------------------------------------------------
__global__ __launch_bounds__(64) void params_kernel(
    const float* __restrict__ param_x, const float* __restrict__ W1,
    const float* __restrict__ b1, const float* __restrict__ W2,
    const float* __restrict__ b2, float* __restrict__ ws,
    float* __restrict__ params_out) {
  int n = blockIdx.x;
  int tid = threadIdx.x;  // 64 threads
  __shared__ float px[64];
  __shared__ float hid[32];
  __shared__ float pv[7];
  __shared__ int tmin_s, tmax_s;

  px[tid] = param_x[n * 64 + tid];
  if (tid == 0) { tmin_s = TT; tmax_s = -1; }
  __syncthreads();
  if (tid < 32) {
    float s = b1[tid];
    #pragma unroll
    for (int k = 0; k < 64; ++k) s += px[k] * W1[k * 32 + tid];
    hid[tid] = tanhf(s);
  }
  __syncthreads();
  if (tid < 7) {
    float s = b2[tid];
    #pragma unroll
    for (int j = 0; j < 32; ++j) s += hid[j] * W2[j * 7 + tid];
    pv[tid] = s;
  }
  __syncthreads();

  float dt      = tanhf(pv[0]) * 6.0f  + 15.0f;
  float dx      = tanhf(pv[1]) * 20.0f + 22.0f;
  float dy      = tanhf(pv[2]) * 16.0f + 24.0f;
  float sigma2  = expf(pv[3]);
  float delta_t = expf(pv[4]) * 0.4f;
  float delta   = expf(pv[5]) * (10.0f / 11.0f);
  float gamma   = 1.0f / (1.0f + expf(-pv[6]));
  float inv2s2  = 1.0f / (2.0f * sigma2);

  if (tid < 20) {
    float mu = dx + ((float)tid - 10.0f) * delta;
    float vals[44];
    float s = 0.0f;
    #pragma unroll
    for (int w = 0; w < 44; ++w) {
      float d = (float)w - mu;
      float e = expf(-d * d * inv2s2);
      vals[w] = e; s += e;
    }
    float inv = 1.0f / fmaxf(s, 1e-8f);
    // transposed layout: fxT[n][w][q]
    float* FxT = ws + FXT_OFF + n * (44 * 20) + tid;
    #pragma unroll
    for (int w = 0; w < 44; ++w) FxT[w * 20] = vals[w] * inv;
  }
  if (tid < 16) {
    float mu = dy + ((float)tid - 8.0f) * delta;
    float vals[64];
    float s = 0.0f;
    #pragma unroll
    for (int h = 0; h < 64; ++h) {
      float d = (float)h - mu;
      float e = expf(-d * d * inv2s2);
      vals[h] = e; s += e;
    }
    float inv = 1.0f / fmaxf(s, 1e-8f);
    float* Fy = ws + FY_OFF + n * (16 * 64) + tid * 64;
    #pragma unroll
    for (int h = 0; h < 64; ++h) Fy[h] = vals[h] * inv;
  }
  if (tid < 30) {
    float mu = dt + ((float)tid - 15.0f) * delta_t;
    float i0f = floorf(mu);
    float frac = mu - i0f;
    int i0 = (int)i0f;
    int i1 = i0 + 1;
    float w0 = (i0 >= 0 && i0 < TT) ? (1.0f - frac) : 0.0f;
    float w1 = (i1 >= 0 && i1 < TT) ? frac : 0.0f;
    int i0c = min(max(i0, 0), TT - 1);
    int i1c = min(max(i1, 0), TT - 1);
    ((int*)(ws + IDX0_OFF))[n * TT + tid] = i0c;
    ((int*)(ws + IDX1_OFF))[n * TT + tid] = i1c;
    ws[TW0_OFF + n * TT + tid] = w0;
    ws[TW1_OFF + n * TT + tid] = w1;
    atomicMin(&tmin_s, i0c);
    atomicMax(&tmax_s, i1c);
  }
  __syncthreads();
  if (tid == 0) {
    // Gaussian support (union over q / p), cutoff exponent 30 -> R = sqrt(60)*sigma
    float R = 7.7459667f * sqrtf(sigma2);
    int wlo = max(0,  (int)floorf(dx - 10.0f * delta - R));
    int whi = min(43, (int)ceilf (dx +  9.0f * delta + R));
    int hlo = max(0,  (int)floorf(dy -  8.0f * delta - R));
    int hhi = min(63, (int)ceilf (dy +  7.0f * delta + R));
    int* rng = (int*)(ws + RNG_OFF) + n * 6;
    rng[0] = wlo & ~3;   // float4-aligned expansion (safe direction)
    rng[1] = whi | 3;
    rng[2] = hlo & ~3;
    rng[3] = hhi | 3;
    rng[4] = tmin_s;     // needed-t range: g[t] read only for t in [tlo,thi]
    rng[5] = tmax_s;

    ws[GAM_OFF + n] = gamma;
    params_out[0 * NN + n] = dt;
    params_out[1 * NN + n] = dx;
    params_out[2 * NN + n] = dy;
    params_out[3 * NN + n] = sigma2;
    params_out[4 * NN + n] = delta;
    params_out[5 * NN + n] = delta_t;
    params_out[6 * NN + n] = gamma;
  }
}

// ---------------------------------------------------------------------------
// Kernel 2 v5: block = (n, t, c-quad).
//   t-skip: blocks with t outside [tlo,thi] exit immediately (g never read
//   there). Stage 1 two-phase: (A) issue ALL in-range chunk loads up front
//   (full memory-level parallelism, as in the 508us version), (B) FMA per
//   chunk behind an SGPR-bounds branch -> s_cbranch skips whole 80-FMA
//   blocks. Accumulation order identical to fma(0,.,s) version.
// Stage 2: g[p][q] = sum_h Fy[p][h]*t1[h][q], 2p x 5q register tile,
//   h-range restricted, half-wave h-split + shfl_xor(32) reduce.
// ---------------------------------------------------------------------------
__global__ __launch_bounds__(256) void spatial_kernel(
    const float* __restrict__ x, const float* __restrict__ ws,
    float* __restrict__ g) {
  int b = blockIdx.x;                 // 0 .. 16*30*16-1
  int n  = b / (TT * 16);
  int r  = b % (TT * 16);
  int t  = r / 16;
  int c0 = (r % 16) * 4;

  int tid  = threadIdx.x;
  int cl   = tid >> 6;        // 0..3
  int lane = tid & 63;

  __shared__ float st1[4 * 20 * 68];  // [cl][q][h], stride 68 (bank-spread)
  __shared__ float sFy[16 * 68];      // [p][h], stride 68

  const int* rng = (const int*)(ws + RNG_OFF) + n * 6;
  // scalarize bounds -> SGPR loop bounds / scalar branches
  int wlo4 = __builtin_amdgcn_readfirstlane(rng[0]);
  int whi4 = __builtin_amdgcn_readfirstlane(rng[1]);
  int hlo4 = __builtin_amdgcn_readfirstlane(rng[2]);
  int hhi4 = __builtin_amdgcn_readfirstlane(rng[3]);
  int tlo  = __builtin_amdgcn_readfirstlane(rng[4]);
  int thi  = __builtin_amdgcn_readfirstlane(rng[5]);

  // t-skip: g[t] never read by output kernel -> whole block no-ops.
  // Uniform branch (t, tlo, thi wave-uniform) before any barrier: safe.
  if (t < tlo || t > thi) return;

  // Load Fy into LDS: one float4 per thread (1024 floats)
  {
    const float4* Fy4 = (const float4*)(ws + FY_OFF + n * (16 * 64));
    float4 v = Fy4[tid];
    int p = tid >> 4, h4 = tid & 15;
    *(float4*)&sFy[p * 68 + h4 * 4] = v;
  }

  // ---- Stage 1, phase A: issue all in-range chunk loads (MLP) ----
  int c = c0 + cl;
  bool hact = (lane >= hlo4) && (lane <= hhi4);
  const float4* xp =
      (const float4*)(x + ((((size_t)n * CC + c) * TT + t) * HH + lane) * WW);
  int ilo = wlo4 >> 2, ihi = whi4 >> 2;   // SGPR

  float xrow[44];
  #pragma unroll
  for (int i = 0; i < 11; ++i) {
    float4 v = make_float4(0.0f, 0.0f, 0.0f, 0.0f);
    if (i >= ilo && i <= ihi) {     // scalar branch
      if (hact) v = xp[i];          // vector exec mask
    }
    xrow[4 * i + 0] = v.x; xrow[4 * i + 1] = v.y;
    xrow[4 * i + 2] = v.z; xrow[4 * i + 3] = v.w;
  }

  // ---- Stage 1, phase B: FMA per chunk, scalar-skip out-of-range ----
  const float* fxt = ws + FXT_OFF + n * (44 * 20);  // wave-uniform
  float acc[20];
  #pragma unroll
  for (int q = 0; q < 20; ++q) acc[q] = 0.0f;

  #pragma unroll
  for (int i = 0; i < 11; ++i) {
    if (i >= ilo && i <= ihi) {     // SGPR cond -> s_cbranch skips 80 FMAs
      const float* fr = fxt + i * 80;
      #pragma unroll
      for (int k = 0; k < 4; ++k) {
        float xv = xrow[4 * i + k];
        #pragma unroll
        for (int q = 0; q < 20; ++q)
          acc[q] = fmaf(xv, fr[k * 20 + q], acc[q]);
      }
    }
  }
  if (hact) {
    #pragma unroll
    for (int q = 0; q < 20; ++q) st1[(cl * 20 + q) * 68 + lane] = acc[q];
  }
  __syncthreads();

  // ---- Stage 2: thread = (hh = lane>>5, pp = (lane>>2)&7, qg = lane&3)
  //      computes p in {pp, pp+8}, q in [qg*5, qg*5+5), partial over its
  //      h-half (interleaved hcc), then shfl_xor(32) combines halves.
  int hh = lane >> 5;
  int pp = (lane >> 2) & 7;
  int qg = lane & 3;
  int hc0 = hlo4 >> 2, hc1 = hhi4 >> 2;   // SGPR bounds

  float o[2][5];
  #pragma unroll
  for (int u = 0; u < 2; ++u)
    #pragma unroll
    for (int j = 0; j < 5; ++j) o[u][j] = 0.0f;

  for (int hcc = hc0 + hh; hcc <= hc1; hcc += 2) {
    float4 fy0 = *(const float4*)&sFy[pp * 68 + hcc * 4];
    float4 fy1 = *(const float4*)&sFy[(pp + 8) * 68 + hcc * 4];
    #pragma unroll
    for (int j = 0; j < 5; ++j) {
      int q = qg * 5 + j;
      float4 tv = *(const float4*)&st1[(cl * 20 + q) * 68 + hcc * 4];
      o[0][j] = fmaf(fy0.x, tv.x,
                fmaf(fy0.y, tv.y, fmaf(fy0.z, tv.z, fmaf(fy0.w, tv.w, o[0][j]))));
      o[1][j] = fmaf(fy1.x, tv.x,
                fmaf(fy1.y, tv.y, fmaf(fy1.z, tv.z, fmaf(fy1.w, tv.w, o[1][j]))));
    }
  }
  #pragma unroll
  for (int u = 0; u < 2; ++u)
    #pragma unroll
    for (int j = 0; j < 5; ++j)
      o[u][j] += __shfl_xor(o[u][j], 32);

  if (hh == 0) {
    float* gout = g + ((size_t)((n * CC + c) * TT + t)) * HW;
    #pragma unroll
    for (int u = 0; u < 2; ++u) {
      int p = pp + u * 8;
      #pragma unroll
      for (int j = 0; j < 5; ++j) gout[p * OUTW + qg * 5 + j] = o[u][j];
    }
  }
}

// ---------------------------------------------------------------------------
// Kernel 3 v3: block = (n, t', hw-half). float4 mix-fill; register-tiled
// 8oc x 5hw micro-GEMM.
// ---------------------------------------------------------------------------
__global__ __launch_bounds__(256) void output_kernel(
    const float* __restrict__ g, const float* __restrict__ ws,
    const float* __restrict__ Wf, const float* __restrict__ bf,
    float* __restrict__ out) {
  int b = blockIdx.x;             // 0 .. 16*30*2-1
  int n    = b / (TT * 2);
  int r    = b % (TT * 2);
  int tp   = r >> 1;
  int hw0  = (r & 1) * 160;
  int tid  = threadIdx.x;

  __shared__ float sWfT[64 * 65];   // [c][oc], pad 65 (16.6 KB)
  __shared__ float smix[64 * 160];  // [c][hw-half]   (40.96 KB)

  // Wf transposed into LDS
  #pragma unroll
  for (int i = tid; i < 64 * 64; i += 256) {
    int oc = i >> 6, c = i & 63;
    sWfT[c * 65 + oc] = Wf[i];
  }

  int i0 = ((const int*)(ws + IDX0_OFF))[n * TT + tp];
  int i1 = ((const int*)(ws + IDX1_OFF))[n * TT + tp];
  float w0 = ws[TW0_OFF + n * TT + tp];
  float w1 = ws[TW1_OFF + n * TT + tp];
  float gamma = ws[GAM_OFF + n];

  // time-resample + gamma into LDS, float4-vectorized (10 iters/thread)
  #pragma unroll
  for (int i4 = tid; i4 < 64 * 40; i4 += 256) {
    int c  = i4 / 40;
    int r4 = i4 - c * 40;
    size_t base = (size_t)(n * CC + c) * TT;
    float4 a  = *(const float4*)(g + (base + i0) * HW + hw0 + r4 * 4);
    float4 bb = *(const float4*)(g + (base + i1) * HW + hw0 + r4 * 4);
    float4 m;
    m.x = gamma * fmaf(w0, a.x, w1 * bb.x);
    m.y = gamma * fmaf(w0, a.y, w1 * bb.y);
    m.z = gamma * fmaf(w0, a.z, w1 * bb.z);
    m.w = gamma * fmaf(w0, a.w, w1 * bb.w);
    *(float4*)&smix[c * 160 + r4 * 4] = m;
  }
  __syncthreads();

  // micro-GEMM: thread tile 8 oc x 5 hw
  int ocg = tid >> 5;           // 0..7  -> oc0 = ocg*8
  int hwg = tid & 31;           // 0..31 -> hwl0 = hwg*5
  int oc0 = ocg * 8;
  int hwl0 = hwg * 5;
  float acc[8][5];
  #pragma unroll
  for (int u = 0; u < 8; ++u)
    #pragma unroll
    for (int j = 0; j < 5; ++j) acc[u][j] = 0.0f;

  #pragma unroll 4
  for (int c = 0; c < 64; ++c) {
    float4 wv0 = *(const float4*)&sWfT[c * 65 + oc0];
    float4 wv1 = *(const float4*)&sWfT[c * 65 + oc0 + 4];
    float m[5];
    #pragma unroll
    for (int j = 0; j < 5; ++j) m[j] = smix[c * 160 + hwl0 + j];
    float wv[8] = {wv0.x, wv0.y, wv0.z, wv0.w, wv1.x, wv1.y, wv1.z, wv1.w};
    #pragma unroll
    for (int u = 0; u < 8; ++u)
      #pragma unroll
      for (int j = 0; j < 5; ++j) acc[u][j] = fmaf(wv[u], m[j], acc[u][j]);
  }

  #pragma unroll
  for (int u = 0; u < 8; ++u) {
    int oc = oc0 + u;
    float bias = bf[oc];
    float* op = out + (((size_t)n * CC + oc) * TT + tp) * HW + hw0 + hwl0;
    #pragma unroll
    for (int j = 0; j < 5; ++j) op[j] = acc[u][j] + bias;
  }
}

// ---------------------------------------------------------------------------
extern "C" void kernel_launch(void* const* d_in, const int* in_sizes, int n_in,
                              void* d_out, int out_size, void* d_ws,
                              size_t ws_size, hipStream_t stream) {
  const float* x       = (const float*)d_in[0];
  const float* param_x = (const float*)d_in[1];
  const float* W1      = (const float*)d_in[2];
  const float* b1      = (const float*)d_in[3];
  const float* W2      = (const float*)d_in[4];
  const float* b2      = (const float*)d_in[5];
  const float* Wf      = (const float*)d_in[6];
  const float* bf      = (const float*)d_in[7];
  float* out = (float*)d_out;
  float* ws  = (float*)d_ws;
  float* params_out = out + (size_t)NN * CC * TT * HW;  // 9830400

  params_kernel<<<NN, 64, 0, stream>>>(param_x, W1, b1, W2, b2, ws, params_out);
  spatial_kernel<<<NN * TT * 16, 256, 0, stream>>>(x, ws, ws + G_OFF);
  output_kernel<<<NN * TT * 2, 256, 0, stream>>>(ws + G_OFF, ws, Wf, bf, out);
}